// Round 8
// baseline (382.823 us; speedup 1.0000x reference)
//
#include <hip/hip_runtime.h>
#include <cstddef>

#define BB 64
#define NN 1024
#define CC 256
#define KK 512
#define TT 64
#define NPAIR 128

typedef _Float16 h8 __attribute__((ext_vector_type(8)));
typedef _Float16 h4 __attribute__((ext_vector_type(4)));
typedef float f4 __attribute__((ext_vector_type(4)));

// async global->LDS, 16B per lane; LDS dest = wave-uniform base + lane*16
typedef __attribute__((address_space(1))) const void GV;
typedef __attribute__((address_space(3))) void LV;
#define GLDS16(g, s) __builtin_amdgcn_global_load_lds((GV*)(const void*)(g), (LV*)(void*)(s), 16, 0, 0)

// ---------------- ws layout (float words) ----------------
// feath   : 0          size 4194304  (8388608 f16: 32768 x 256 hi)
// featl   : 4194304    size 4194304  (lo plane)
// normF   : 8388608    size 32768   (zeroed via hipMemsetAsync; feat atomically accumulates)
// centk   : 8421376    size B*K*4   = 131072   (x,y,z,|c|^2)
// sbuf    : 8552448    size 65536   (T*2*K)
// topidx  : 8617984    size 32768   (int)
// neff    : 8650752    size 64      (int)
// gmask   : 8716352    size NPAIR*K*16 = 1048576 (uint)
//   wth/wtl alias gmask top (+786432 / +819200) - consumed by feat before geo
// partv   : 9764928    size 131072 (2-way partials; dead after geo -> evg reuses)
// partl   : 10027072
// partd   : 10289216
// evg     : 9764928    (aliases partv; 128*512 floats, written by power, read by tail)
// total 10551360 words = 42.2 MB
//
// LDS chunk swizzle (argmin/feat tiles): a [R][32] f16 tile has 64-B rows of
// four 16-B chunks. Reads are "16 consecutive rows, same chunk" -> ~8-way bank
// serialization. Swizzle chunk c -> c ^ ((row>>1)&3) (involution), applied on
// BOTH the staging side (pre-swizzled global source for global_load_lds /
// swizzled dest for explicit stores) and the read side -> 2 lanes/bank (free).
// Verified R7: SQ_LDS_BANK_CONFLICT 3.16M -> 12K.

// ===================== stage 0: W_in transpose + f16 split =====================
__global__ __launch_bounds__(256) void wtrans_kernel(
    const float* __restrict__ Win, _Float16* __restrict__ wth, _Float16* __restrict__ wtl)
{
    __shared__ float t[64][65];
    const int k0 = blockIdx.x * 64, n0 = blockIdx.y * 64;
    const int tid = threadIdx.x;
    const int c = tid & 63, r0 = tid >> 6;
    for (int r = r0; r < 64; r += 4)
        t[r][c] = Win[(size_t)(k0 + r) * CC + n0 + c];
    __syncthreads();
    for (int r = r0; r < 64; r += 4) {
        float x = t[c][r];                     // x = Win[k0+c][n0+r]
        _Float16 h = (_Float16)x;
        size_t o = (size_t)(n0 + r) * CC + k0 + c;
        wth[o] = h;
        wtl[o] = (_Float16)(x - (float)h);
    }
}

// ===================== stage 1: selection =====================
__global__ __launch_bounds__(512) void sel_kernel(
    const float* __restrict__ attn, const float* __restrict__ cents,
    const float* __restrict__ sas, const int* __restrict__ num_rt,
    int* __restrict__ topidx, int* __restrict__ neff, float* __restrict__ centk)
{
    __shared__ unsigned long long keys[1024];
    const int b = blockIdx.x, tid = threadIdx.x;
    const int nr = num_rt[b];
    for (int i = tid; i < 1024; i += 512) {
        float a = (i < nr) ? attn[b * NN + i] : -1e9f;
        unsigned u = __float_as_uint(a);
        u = (u & 0x80000000u) ? ~u : (u | 0x80000000u);
        keys[i] = ((unsigned long long)u << 32) | (unsigned)(0xFFFFFFFFu - (unsigned)i);
    }
    __syncthreads();
    for (int k = 2; k <= 1024; k <<= 1) {
        for (int j = k >> 1; j > 0; j >>= 1) {
            int i = ((tid & ~(j - 1)) << 1) | (tid & (j - 1));
            int p = i | j;
            unsigned long long a = keys[i], c = keys[p];
            bool up = (i & k) == 0;
            if (up ? (a < c) : (a > c)) { keys[i] = c; keys[p] = a; }
            __syncthreads();
        }
    }
    {
        unsigned long long key = keys[tid];
        int idx = (int)(~(unsigned)key);
        float x = cents[(b * NN + idx) * 3 + 0];
        float y = cents[(b * NN + idx) * 3 + 1];
        float z = cents[(b * NN + idx) * 3 + 2];
        if (idx < nr) {
            float sc = sas[b * 4 + 3];
            x = x * sc + sas[b * 4 + 0];
            y = y * sc + sas[b * 4 + 1];
            z = z * sc + sas[b * 4 + 2];
        }
        float nc = x * x + y * y + z * z;
        ((float4*)centk)[b * KK + tid] = make_float4(x, y, z, nc);
        topidx[b * KK + tid] = idx;
    }
    if (tid == 0) neff[b] = (nr < KK) ? nr : KK;
}

// ===================== stage 2: feat = rt_k @ W_in + b_in via split-f16 MFMA ====
// Fused row-norm epilogue (deterministic: exactly 2 commutative atomic adds per
// row). LDS tiles chunk-swizzled (see header comment).
__global__ __launch_bounds__(256) void feat_mfma(
    const float* __restrict__ rt, const int* __restrict__ topidx,
    const _Float16* __restrict__ wth, const _Float16* __restrict__ wtl,
    const float* __restrict__ bin,
    _Float16* __restrict__ feath, _Float16* __restrict__ featl,
    float* __restrict__ normF)
{
    const int mtile = blockIdx.x, nt = blockIdx.y;
    __shared__ _Float16 Ah[128][32], Al[128][32], Bh[128][32], Bl[128][32];
    __shared__ int tix[128];
    __shared__ float rowpart[128][2];
    const int tid = threadIdx.x;
    const int w = tid >> 6, lane = tid & 63;
    const int quad = lane >> 4, l16 = lane & 15;
    const int wm = (w >> 1) * 64, wl = (w & 1) * 64;
    const int b = mtile >> 2;
    if (tid < 128) tix[tid] = topidx[mtile * 128 + tid];
    __syncthreads();
    const int arow_i = tid >> 1;              // A row this thread converts
    const int aseg = (tid & 1) * 16;          // 16-col half of that row
    const int asw = (arow_i >> 1) & 3;        // store-side swizzle for this row
    const float* arow = rt + ((size_t)b * NN + tix[arow_i]) * CC + aseg;
    _Float16* bsh = (w < 2) ? &Bh[0][0] : &Bl[0][0];
    const _Float16* bplane = (w < 2) ? wth : wtl;
    const int rowi = lane >> 2, chunk = lane & 3;
    const int ssw = (rowi >> 1) & 3;          // staging source swizzle (GLDS16)
    const int rsw = (l16 >> 1) & 3;           // read-side swizzle

    f4 acc[4][4];
    #pragma unroll
    for (int i = 0; i < 4; i++)
        #pragma unroll
        for (int j = 0; j < 4; j++)
            acc[i][j] = (f4){0.f, 0.f, 0.f, 0.f};

    for (int k0 = 0; k0 < CC; k0 += 32) {
        __syncthreads();
        // B async first (4 wave-loads per wave); source chunk pre-swizzled
        #pragma unroll
        for (int jj = 0; jj < 4; jj++) {
            int j = (w & 1) * 4 + jj;
            int row = j * 16 + rowi;
            GLDS16(bplane + (size_t)(nt * 128 + row) * CC + k0 + (chunk ^ ssw) * 8, bsh + j * 512);
        }
        // A convert (every thread); dest chunk swizzled
        {
            const float4* src = (const float4*)(arow + k0);
            #pragma unroll
            for (int c = 0; c < 2; c++) {
                float4 p = src[2 * c], q2 = src[2 * c + 1];
                float xv[8] = {p.x, p.y, p.z, p.w, q2.x, q2.y, q2.z, q2.w};
                h8 hv, lv;
                #pragma unroll
                for (int j = 0; j < 8; j++) {
                    _Float16 h = (_Float16)xv[j];
                    hv[j] = h;
                    lv[j] = (_Float16)(xv[j] - (float)h);
                }
                int ci = ((tid & 1) * 2 + c) ^ asw;
                *(h8*)&Ah[arow_i][ci * 8] = hv;
                *(h8*)&Al[arow_i][ci * 8] = lv;
            }
        }
        __syncthreads();
        h8 afh[4], afl[4], bfh[4], bfl[4];
        #pragma unroll
        for (int i = 0; i < 4; i++) {
            int ra = wm + i * 16 + l16;
            int rb = wl + i * 16 + l16;
            int qa = (quad ^ rsw) * 8;
            afh[i] = *(const h8*)&Ah[ra][qa];
            afl[i] = *(const h8*)&Al[ra][qa];
            bfh[i] = *(const h8*)&Bh[rb][qa];
            bfl[i] = *(const h8*)&Bl[rb][qa];
        }
        #pragma unroll
        for (int i = 0; i < 4; i++)
            #pragma unroll
            for (int j = 0; j < 4; j++) {
                acc[i][j] = __builtin_amdgcn_mfma_f32_16x16x32_f16(afh[i], bfh[j], acc[i][j], 0, 0, 0);
                acc[i][j] = __builtin_amdgcn_mfma_f32_16x16x32_f16(afh[i], bfl[j], acc[i][j], 0, 0, 0);
                acc[i][j] = __builtin_amdgcn_mfma_f32_16x16x32_f16(afl[i], bfh[j], acc[i][j], 0, 0, 0);
            }
    }
    float rowsq[4][4];
    #pragma unroll
    for (int i = 0; i < 4; i++)
        #pragma unroll
        for (int r = 0; r < 4; r++)
            rowsq[i][r] = 0.f;
    #pragma unroll
    for (int j = 0; j < 4; j++) {
        int col = wl + j * 16 + l16;
        float bj = bin[nt * 128 + col];
        #pragma unroll
        for (int i = 0; i < 4; i++)
            #pragma unroll
            for (int r = 0; r < 4; r++) {
                int row = wm + i * 16 + quad * 4 + r;
                float v = acc[i][j][r] + bj;
                rowsq[i][r] += v * v;
                _Float16 h = (_Float16)v;
                size_t o = (size_t)(mtile * 128 + row) * CC + nt * 128 + col;
                feath[o] = h;
                featl[o] = (_Float16)(v - (float)h);
            }
    }
    // per-row norm partials: reduce over the 16 l16-lanes, stash per wave-half
    #pragma unroll
    for (int i = 0; i < 4; i++)
        #pragma unroll
        for (int r = 0; r < 4; r++) {
            float p = rowsq[i][r];
            #pragma unroll
            for (int off = 1; off < 16; off <<= 1)
                p += __shfl_xor(p, off);
            if (l16 == 0)
                rowpart[wm + i * 16 + quad * 4 + r][w & 1] = p;
        }
    __syncthreads();
    if (tid < 128) {
        float nf = rowpart[tid][0] + rowpart[tid][1];
        atomicAdd(normF + mtile * 128 + tid, nf);   // exactly 2 adds/row (nt=0,1)
    }
}

// ===================== stage 3: fd argmin, 256x256 tile, 16 waves ===============
// v8: 1024 threads, 4x4 wave grid (each wave 64x64 output, acc 64 f32/thread)
// -> unified regs <=128 -> 16 waves/CU (4/SIMD), 2x TLP vs the 8-wave version.
// Counted-vmcnt 2-phase pipeline kept (4 loads/wave, vmcnt(4)); chunk swizzle
// kept; reduction arrays aliased onto the dead staging buffer (LDS = 128 KiB).
// Per-(k,l) fd values come from the identical MFMA sequence -> bit-exact; the
// argmin merge scans wc ascending then lt ascending -> identical tie-breaks.
__global__ __launch_bounds__(1024, 4) void argmin_mfma(
    const _Float16* __restrict__ feath, const _Float16* __restrict__ featl,
    const float* __restrict__ normF,
    const int* __restrict__ anc, const int* __restrict__ pos, const int* __restrict__ neg,
    float* __restrict__ partv, int* __restrict__ partl, float* __restrict__ partd)
{
    // bijective XCD decode: id = xcd + 8*((pr%16)*4 + s), pr = xcd*16 + ...
    const int id = blockIdx.x;
    const int xcd = id & 7, kgrp = id >> 3;
    const int pr = xcd * 16 + (kgrp >> 2);
    const int s = kgrp & 3;
    const int lt = s & 1, kt = s >> 1;
    const int t = pr >> 1, nn2 = pr & 1;
    const int a = anc[t];
    const int bb = nn2 ? neg[t] : pos[t];
    const size_t Abase = ((size_t)a * KK + kt * 256) * CC;
    const size_t Bbase = ((size_t)bb * KK + lt * 256) * CC;
    // S[buf][plane][256*32]; plane: 0=Ah 1=Al 2=Bh 3=Bl ; 128 KiB total
    __shared__ _Float16 S[2][4][8192];
    // reduction arrays alias the staging buffer (dead after the K-loop)
    float* rdv = (float*)&S[0][0][0];          // 256*4 floats
    int*   rdl = (int*)(rdv + 1024);           // 256*4 ints
    float* rdd = (float*)(rdl + 1024);         // 256*4 floats
    const int tid = threadIdx.x;
    const int w = tid >> 6, lane = tid & 63;
    const int quad = lane >> 4, l16 = lane & 15;
    const int wr = w >> 2, wc = w & 3;          // wave tile: rows wr*64, cols wc*64
    const int rowi = lane >> 2, chunk = lane & 3;
    const int ssw = (rowi >> 1) & 3;            // staging source swizzle
    const int rsw = (l16 >> 1) & 3;             // read-side swizzle
    // staging role: wave w stages plane w>>2, rows (w&3)*64 .. +63 (4 loads)
    const int plane = w >> 2;
    const int srow = (w & 3) * 64;
    const _Float16* gsrc = (plane == 0) ? feath + Abase
                         : (plane == 1) ? featl + Abase
                         : (plane == 2) ? feath + Bbase
                         :                featl + Bbase;
    const _Float16* grow = gsrc + (size_t)(srow + rowi) * CC + (chunk ^ ssw) * 8;

    f4 acc[4][4];
    #pragma unroll
    for (int i = 0; i < 4; i++)
        #pragma unroll
        for (int j = 0; j < 4; j++)
            acc[i][j] = (f4){0.f, 0.f, 0.f, 0.f};

    // prologue: stage K-step 0 into buffer 0 (4 loads/wave -> vmcnt 4)
    #pragma unroll
    for (int j = 0; j < 4; j++)
        GLDS16(grow + (size_t)(j * 16) * CC, &S[0][plane][srow * 32 + j * 512]);

    #pragma unroll
    for (int kk = 0; kk < 8; kk++) {
        const int cb = kk & 1;
        // issue next K-step's 4 loads, then wait only for the previous 4
        if (kk < 7) {
            const int k1 = (kk + 1) * 32;
            #pragma unroll
            for (int j = 0; j < 4; j++)
                GLDS16(grow + (size_t)(j * 16) * CC + k1, &S[cb ^ 1][plane][srow * 32 + j * 512]);
            asm volatile("s_waitcnt vmcnt(4)" ::: "memory");
        } else {
            asm volatile("s_waitcnt vmcnt(0)" ::: "memory");
        }
        __builtin_amdgcn_s_barrier();          // buffer cb ready for all waves
        const int qa = (quad ^ rsw) * 8;
        h8 afh[4], afl[4];
        #pragma unroll
        for (int i = 0; i < 4; i++) {
            int ra = wr * 64 + i * 16 + l16;
            afh[i] = *(const h8*)&S[cb][0][ra * 32 + qa];
            afl[i] = *(const h8*)&S[cb][1][ra * 32 + qa];
        }
        #pragma unroll
        for (int j = 0; j < 4; j++) {
            int rb = wc * 64 + j * 16 + l16;
            h8 bfh = *(const h8*)&S[cb][2][rb * 32 + qa];
            h8 bfl = *(const h8*)&S[cb][3][rb * 32 + qa];
            #pragma unroll
            for (int i = 0; i < 4; i++) {
                acc[i][j] = __builtin_amdgcn_mfma_f32_16x16x32_f16(afh[i], bfh, acc[i][j], 0, 0, 0);
                acc[i][j] = __builtin_amdgcn_mfma_f32_16x16x32_f16(afh[i], bfl, acc[i][j], 0, 0, 0);
                acc[i][j] = __builtin_amdgcn_mfma_f32_16x16x32_f16(afl[i], bfh, acc[i][j], 0, 0, 0);
            }
        }
        __builtin_amdgcn_sched_barrier(0);     // pin reads/MFMA before WAR barrier
        __builtin_amdgcn_s_barrier();          // all waves done reading buf cb
    }
    float nbj[4];
    #pragma unroll
    for (int j = 0; j < 4; j++)
        nbj[j] = normF[(size_t)bb * KK + lt * 256 + wc * 64 + j * 16 + l16];
    #pragma unroll
    for (int i = 0; i < 4; i++) {
        #pragma unroll
        for (int r = 0; r < 4; r++) {
            float bv = INFINITY; int bl = 0; float bd = 0.f;
            #pragma unroll
            for (int j = 0; j < 4; j++) {
                float d = acc[i][j][r];
                float v = nbj[j] - 2.f * d;
                int l = lt * 256 + wc * 64 + j * 16 + l16;
                if (v < bv) { bv = v; bl = l; bd = d; }
            }
            #pragma unroll
            for (int off = 1; off < 16; off <<= 1) {
                float ov = __shfl_xor(bv, off);
                int   ol = __shfl_xor(bl, off);
                float od = __shfl_xor(bd, off);
                if (ov < bv || (ov == bv && ol < bl)) { bv = ov; bl = ol; bd = od; }
            }
            if (l16 == 0) {
                int row = wr * 64 + i * 16 + quad * 4 + r;
                rdv[row * 4 + wc] = bv;
                rdl[row * 4 + wc] = bl;
                rdd[row * 4 + wc] = bd;
            }
        }
    }
    __syncthreads();
    if (tid < 256) {
        float bv = rdv[tid * 4 + 0]; int bl = rdl[tid * 4 + 0]; float bd = rdd[tid * 4 + 0];
        #pragma unroll
        for (int wcc = 1; wcc < 4; wcc++) {
            float v = rdv[tid * 4 + wcc]; int l = rdl[tid * 4 + wcc];
            if (v < bv || (v == bv && l < bl)) { bv = v; bl = l; bd = rdd[tid * 4 + wcc]; }
        }
        size_t idx = ((size_t)pr * KK + kt * 256 + tid) * 2 + lt;
        partv[idx] = bv; partl[idx] = bl; partd[idx] = bd;
    }
}

// ===================== stage 4: geo bitmask (argmin_fin fused) =====================
__global__ __launch_bounds__(256) void geo_kernel(
    const float* __restrict__ centk,
    const float* __restrict__ partv, const int* __restrict__ partl,
    const float* __restrict__ partd, const float* __restrict__ normF,
    const int* __restrict__ neff,
    const int* __restrict__ anc, const int* __restrict__ pos, const int* __restrict__ neg,
    float* __restrict__ sbuf, unsigned* __restrict__ gmask)
{
    const int kt = blockIdx.x;          // 0..1 (256 rows)
    const int lt4 = blockIdx.y;         // 0..3 (128 cols)
    const int pair = blockIdx.z;        // 0..127
    const int t = pair >> 1, nn2 = pair & 1;
    const int a = anc[t];
    const int bb2 = (nn2 == 0) ? pos[t] : neg[t];
    const int nea = neff[a], neb = neff[bb2];
    const bool writer = (kt == 0) && (lt4 == 0);
    __shared__ int ci[512];
    __shared__ __align__(16) float4 ca[512], cq[512];
    // fused argmin_fin: merge the 2 l-tile partials (identical tie-break order)
    for (int i = threadIdx.x; i < KK; i += 256) {
        size_t base = ((size_t)pair * KK + i) * 2;
        float bv = partv[base]; int bl = partl[base]; float bd = partd[base];
        float v = partv[base + 1]; int l = partl[base + 1];
        if (v < bv || (v == bv && l < bl)) { bv = v; bl = l; bd = partd[base + 1]; }
        ci[i] = bl;
        if (writer) {
            float na = normF[(size_t)a * KK + i];
            float nb = normF[(size_t)bb2 * KK + bl];
            float cosv = bd / (sqrtf(na) * sqrtf(nb) + 1e-8f);
            sbuf[pair * KK + i] = fmaxf(cosv, 0.f);
        }
    }
    __syncthreads();
    for (int i = threadIdx.x; i < KK; i += 256) {
        ca[i] = ((const float4*)centk)[a * KK + i];
        cq[i] = ((const float4*)centk)[bb2 * KK + ci[i]];
    }
    __syncthreads();
    const int k = kt * 256 + threadIdx.x;
    float4 pk = ca[k], qk = cq[k];
    bool rowm = k < nea;
    unsigned* outp = gmask + ((size_t)pair * KK + k) * 16 + lt4 * 4;
    for (int w = 0; w < 4; w++) {
        unsigned word = 0;
        #pragma unroll
        for (int bi = 0; bi < 32; bi++) {
            int l = lt4 * 128 + w * 32 + bi;
            float4 pl = ca[l], ql = cq[l];
            float dp2 = pk.w + pl.w - 2.f * (pk.x * pl.x + pk.y * pl.y + pk.z * pl.z);
            float dp = sqrtf(fmaxf(dp2, 0.f) + 1e-12f);
            float dq2 = qk.w + ql.w - 2.f * (qk.x * ql.x + qk.y * ql.y + qk.z * ql.z);
            float dq = sqrtf(fmaxf(dq2, 0.f) + 1e-12f);
            bool g = (fabsf(dp - dq) < 0.5f) && rowm && (l < neb) && (l != k);
            word |= (g ? (1u << bi) : 0u);
        }
        outp[w] = word;
    }
}

// ===================== stage 5a: power iteration (tail split out) ==============
__global__ __launch_bounds__(1024, 4) void power_kernel(
    const unsigned* __restrict__ gmask, const float* __restrict__ sbuf,
    const int* __restrict__ neff,
    const int* __restrict__ anc, const int* __restrict__ pos, const int* __restrict__ neg,
    float* __restrict__ evg)
{
    const int pair = blockIdx.x;
    const int tid = threadIdx.x;
    const int row = tid & 511;
    const int half = tid >> 9;
    const int tt = pair >> 1, nn2 = pair & 1;
    const int a = anc[tt];
    const int bb2 = (nn2 == 0) ? pos[tt] : neg[tt];
    const int nea = neff[a], neb = neff[bb2];
    __shared__ __align__(16) float uu[512];    // split layout, see UADDR
    __shared__ float T[64][257];
    __shared__ float pacc[1024];
    __shared__ float red[16];
    __shared__ int convflag;
    unsigned m[8];
    const unsigned* g = gmask + ((size_t)pair * KK + row) * 16 + half * 8;
    #pragma unroll
    for (int w = 0; w < 8; w++) m[w] = g[w];
    const float s = sbuf[pair * KK + row];
    // wave-uniform activity: this wave's 64-row span entirely >= nea -> skip
    const int wbase = tid & 511 & ~63;
    const bool wact = (wbase < nea);
    // block-uniform: number of nonzero 32-col words in this half
    int nw = (neb - half * 256 + 31) >> 5;
    nw = (nw < 0) ? 0 : (nw > 8 ? 8 : nw);
    const int bp = tid & 63;
    const int vh = tid >> 6;
    // split-u address: read side lane bp reads uu[4*bp..+3] and uu[256+4*bp..+3]
    // -> stride-16B ds_read_b128, conflict-free.
    #define UADDR(r) ((((r) & 4) << 6) + (((r) >> 3) << 2) + ((r) & 3))
    const int GV_[16] = {0,1,3,2,6,7,5,4,12,13,15,14,10,11,9,8};
    const int GB[15] = {0,1,0,2,0,1,0,3,0,1,0,2,0,1,0};
    const float GS[15] = {1.f,1.f,-1.f,1.f,1.f,-1.f,-1.f,1.f,1.f,1.f,-1.f,-1.f,1.f,-1.f,-1.f};
    float v = 0.044194173824159216f;   // 1/sqrt(512)
    float vnprev = v;                  // previous NORMALIZED v
    if (half == 0) uu[UADDR(row)] = s * v;
    __syncthreads();
    for (int it = 0; it < 20; it++) {
        {
            float4 ulo = *(const float4*)&uu[bp * 4];
            float4 uhi = *(const float4*)&uu[256 + bp * 4];
            float ul[4] = {ulo.x, ulo.y, ulo.z, ulo.w};
            float H = 0.f;
            H += (float)((vh >> 0) & 1) * uhi.x;
            H += (float)((vh >> 1) & 1) * uhi.y;
            H += (float)((vh >> 2) & 1) * uhi.z;
            H += (float)((vh >> 3) & 1) * uhi.w;
            float L = 0.f;
            T[bp][vh * 16 + 0] = H;
            #pragma unroll
            for (int k = 1; k < 16; k++) {
                L += GS[k - 1] * ul[GB[k - 1]];
                T[bp][vh * 16 + GV_[k]] = H + L;
            }
        }
        __syncthreads();
        float a0 = 0.f, a1 = 0.f, a2 = 0.f, a3 = 0.f;
        if (wact) {
            #define GATHERW(w)  do { unsigned mw = m[w]; \
                const int p0 = half * 32 + (w) * 4; \
                a0 += T[p0 + 0][mw & 255u]; \
                a1 += T[p0 + 1][(mw >> 8) & 255u]; \
                a2 += T[p0 + 2][(mw >> 16) & 255u]; \
                a3 += T[p0 + 3][mw >> 24]; } while (0)
            if (nw > 0) GATHERW(0);
            if (nw > 1) GATHERW(1);
            if (nw > 2) GATHERW(2);
            if (nw > 3) GATHERW(3);
            if (nw > 4) GATHERW(4);
            if (nw > 5) GATHERW(5);
            if (nw > 6) GATHERW(6);
            if (nw > 7) GATHERW(7);
            #undef GATHERW
        }
        pacc[tid] = (a0 + a1) + (a2 + a3);
        __syncthreads();
        float wk = s * (pacc[row] + pacc[row + 512]);
        if ((it & 3) == 3) {
            // full normalization (exact reference formula)
            float t2 = wk * wk;
            for (int off = 32; off; off >>= 1) t2 += __shfl_down(t2, off);
            if ((tid & 63) == 0) red[tid >> 6] = t2;
            if (tid == 0) convflag = 1;
            __syncthreads();
            float tot = 0.f;
            #pragma unroll
            for (int x = 0; x < 16; x++) tot += red[x];
            tot *= 0.5f;
            v = wk / (sqrtf(tot) + 1e-8f);
            bool eq = (__float_as_uint(v) == __float_as_uint(vnprev));
            vnprev = v;
            if (half == 0) uu[UADDR(row)] = s * v;
            if (!eq) convflag = 0;
            __syncthreads();
            if (convflag) break;   // bitwise fixed point: remaining iters identity
        } else {
            // deferred: direction-only update (linear iteration)
            if (half == 0) uu[UADDR(row)] = s * wk;
            __syncthreads();
        }
    }
    if (half == 0) evg[(size_t)pair * KK + row] = v;
}

// ===================== stage 5b: sort + MLP tail ===============================
__global__ __launch_bounds__(1024, 4) void tail_kernel(
    const float* __restrict__ evg,
    const float* __restrict__ W1, const float* __restrict__ b1,
    const float* __restrict__ W2, const float* __restrict__ b2,
    float* __restrict__ out)
{
    const int pair = blockIdx.x;
    const int tid = threadIdx.x;
    const int row = tid & 511;
    const int half = tid >> 9;
    __shared__ float red[16];
    __shared__ float ev[512];
    __shared__ float hpart[1024];
    if (half == 0) ev[row] = evg[(size_t)pair * KK + row];
    __syncthreads();
    for (int kk = 2; kk <= 512; kk <<= 1) {
        for (int j = kk >> 1; j; j >>= 1) {
            if (tid < 256) {
                int i = ((tid & ~(j - 1)) << 1) | (tid & (j - 1));
                int p = i | j;
                float x = ev[i], y = ev[p];
                bool up = (i & kk) == 0;
                if (up ? (x < y) : (x > y)) { ev[i] = y; ev[p] = x; }
            }
            __syncthreads();
        }
    }
    const int cbase = half * 256;
    float h = (half == 0) ? b1[row] : 0.f;
    #pragma unroll 8
    for (int l = 0; l < 256; l++)
        h += ev[cbase + l] * W1[(size_t)(cbase + l) * KK + row];
    hpart[tid] = h;
    __syncthreads();
    float term = 0.f;
    if (half == 0) {
        float hv = fmaxf(hpart[row] + hpart[row + 512], 0.f);
        term = hv * W2[row];
    }
    for (int off = 32; off; off >>= 1) term += __shfl_down(term, off);
    if ((tid & 63) == 0) red[tid >> 6] = term;
    __syncthreads();
    if (tid == 0) {
        float sc = 0.f;
        #pragma unroll
        for (int x = 0; x < 16; x++) sc += red[x];
        sc += b2[0];
        out[pair] = 1.f / (1.f + expf(-sc));
        out[NPAIR + pair] = (pair & 1) ? 0.f : 1.f;
    }
}

extern "C" void kernel_launch(void* const* d_in, const int* in_sizes, int n_in,
                              void* d_out, int out_size, void* d_ws, size_t ws_size,
                              hipStream_t stream) {
    (void)in_sizes; (void)n_in; (void)out_size; (void)ws_size;
    const float* rt    = (const float*)d_in[0];
    const float* cents = (const float*)d_in[1];
    const float* attn  = (const float*)d_in[2];
    const float* sas   = (const float*)d_in[3];
    const int* num_rt  = (const int*)d_in[4];
    const int* anc     = (const int*)d_in[5];
    const int* pos     = (const int*)d_in[6];
    const int* neg     = (const int*)d_in[7];
    const float* Win   = (const float*)d_in[8];
    const float* bin   = (const float*)d_in[9];
    const float* W1    = (const float*)d_in[10];
    const float* b1    = (const float*)d_in[11];
    const float* W2    = (const float*)d_in[12];
    const float* b2    = (const float*)d_in[13];

    float* ws = (float*)d_ws;
    _Float16* feath = (_Float16*)ws;
    _Float16* featl = (_Float16*)(ws + 4194304);
    float* normF = ws + 8388608;
    float* centk = ws + 8421376;
    float* sbuf  = ws + 8552448;
    int* topidx  = (int*)(ws + 8617984);
    int* neffp   = (int*)(ws + 8650752);
    unsigned* gmask = (unsigned*)(ws + 8716352);
    _Float16* wth = (_Float16*)(ws + 8716352 + 786432);
    _Float16* wtl = (_Float16*)(ws + 8716352 + 819200);
    float* partv = (float*)(ws + 9764928);
    int*   partl = (int*)(ws + 10027072);
    float* partd = (float*)(ws + 10289216);
    float* evg   = (float*)(ws + 9764928);   // aliases partv (dead after geo)
    float* out = (float*)d_out;

    hipMemsetAsync(normF, 0, 32768 * sizeof(float), stream);
    wtrans_kernel<<<dim3(4, 4), 256, 0, stream>>>(Win, wth, wtl);
    sel_kernel<<<64, 512, 0, stream>>>(attn, cents, sas, num_rt, topidx, neffp, centk);
    feat_mfma<<<dim3(256, 2), 256, 0, stream>>>(rt, topidx, wth, wtl, bin, feath, featl, normF);
    argmin_mfma<<<512, 1024, 0, stream>>>(feath, featl, normF, anc, pos, neg, partv, partl, partd);
    geo_kernel<<<dim3(2, 4, 128), 256, 0, stream>>>(centk, partv, partl, partd, normF, neffp, anc, pos, neg, sbuf, gmask);
    power_kernel<<<128, 1024, 0, stream>>>(gmask, sbuf, neffp, anc, pos, neg, evg);
    tail_kernel<<<128, 1024, 0, stream>>>(evg, W1, b1, W2, b2, out);
}

// Round 9
// 342.695 us; speedup vs baseline: 1.1171x; 1.1171x over previous
//
#include <hip/hip_runtime.h>
#include <cstddef>

#define BB 64
#define NN 1024
#define CC 256
#define KK 512
#define TT 64
#define NPAIR 128

typedef _Float16 h8 __attribute__((ext_vector_type(8)));
typedef _Float16 h4 __attribute__((ext_vector_type(4)));
typedef float f4 __attribute__((ext_vector_type(4)));

// async global->LDS, 16B per lane; LDS dest = wave-uniform base + lane*16
typedef __attribute__((address_space(1))) const void GV;
typedef __attribute__((address_space(3))) void LV;
#define GLDS16(g, s) __builtin_amdgcn_global_load_lds((GV*)(const void*)(g), (LV*)(void*)(s), 16, 0, 0)

// ---------------- ws layout (float words) ----------------
// feath   : 0          size 4194304  (8388608 f16: 32768 x 256 hi)
// featl   : 4194304    size 4194304  (lo plane)
// normF   : 8388608    size 32768
// centk   : 8421376    size B*K*4   = 131072   (x,y,z,|c|^2)
// sbuf    : 8552448    size 65536   (T*2*K)
// topidx  : 8617984    size 32768   (int)
// neff    : 8650752    size 64      (int)
// gmask   : 8716352    size NPAIR*K*16 = 1048576 (uint)
//   wth/wtl alias gmask top (+786432 / +819200) - consumed by feat before geo
// partv   : 9764928    size 131072 (2-way partials)
// partl   : 10027072
// partd   : 10289216
// total 10551360 words = 42.2 MB
//
// LDS chunk swizzle (argmin/feat tiles): a [R][32] f16 tile has 64-B rows of
// four 16-B chunks. Reads are "16 consecutive rows, same chunk" -> ~8-way bank
// serialization. Swizzle chunk c -> c ^ ((row>>1)&3) (involution), applied on
// BOTH the staging side (pre-swizzled global source for global_load_lds /
// swizzled dest for explicit stores) and the read side -> 2 lanes/bank (free).
// Verified R7: SQ_LDS_BANK_CONFLICT 3.16M -> 12K, bit-exact.
//
// R8 lesson (kept as a constraint): 1024-thread argmin blocks force <=128
// regs/wave; the pipelined K-loop does not fit -> compiler spills acc to
// scratch (92 MB WRITE_SIZE, 69->91 us). Stay at 512 threads / 8 waves.

// ===================== stage 0: W_in transpose + f16 split =====================
__global__ __launch_bounds__(256) void wtrans_kernel(
    const float* __restrict__ Win, _Float16* __restrict__ wth, _Float16* __restrict__ wtl)
{
    __shared__ float t[64][65];
    const int k0 = blockIdx.x * 64, n0 = blockIdx.y * 64;
    const int tid = threadIdx.x;
    const int c = tid & 63, r0 = tid >> 6;
    for (int r = r0; r < 64; r += 4)
        t[r][c] = Win[(size_t)(k0 + r) * CC + n0 + c];
    __syncthreads();
    for (int r = r0; r < 64; r += 4) {
        float x = t[c][r];                     // x = Win[k0+c][n0+r]
        _Float16 h = (_Float16)x;
        size_t o = (size_t)(n0 + r) * CC + k0 + c;
        wth[o] = h;
        wtl[o] = (_Float16)(x - (float)h);
    }
}

// ===================== stage 1: selection =====================
__global__ __launch_bounds__(512) void sel_kernel(
    const float* __restrict__ attn, const float* __restrict__ cents,
    const float* __restrict__ sas, const int* __restrict__ num_rt,
    int* __restrict__ topidx, int* __restrict__ neff, float* __restrict__ centk)
{
    __shared__ unsigned long long keys[1024];
    const int b = blockIdx.x, tid = threadIdx.x;
    const int nr = num_rt[b];
    for (int i = tid; i < 1024; i += 512) {
        float a = (i < nr) ? attn[b * NN + i] : -1e9f;
        unsigned u = __float_as_uint(a);
        u = (u & 0x80000000u) ? ~u : (u | 0x80000000u);
        keys[i] = ((unsigned long long)u << 32) | (unsigned)(0xFFFFFFFFu - (unsigned)i);
    }
    __syncthreads();
    for (int k = 2; k <= 1024; k <<= 1) {
        for (int j = k >> 1; j > 0; j >>= 1) {
            int i = ((tid & ~(j - 1)) << 1) | (tid & (j - 1));
            int p = i | j;
            unsigned long long a = keys[i], c = keys[p];
            bool up = (i & k) == 0;
            if (up ? (a < c) : (a > c)) { keys[i] = c; keys[p] = a; }
            __syncthreads();
        }
    }
    {
        unsigned long long key = keys[tid];
        int idx = (int)(~(unsigned)key);
        float x = cents[(b * NN + idx) * 3 + 0];
        float y = cents[(b * NN + idx) * 3 + 1];
        float z = cents[(b * NN + idx) * 3 + 2];
        if (idx < nr) {
            float sc = sas[b * 4 + 3];
            x = x * sc + sas[b * 4 + 0];
            y = y * sc + sas[b * 4 + 1];
            z = z * sc + sas[b * 4 + 2];
        }
        float nc = x * x + y * y + z * z;
        ((float4*)centk)[b * KK + tid] = make_float4(x, y, z, nc);
        topidx[b * KK + tid] = idx;
    }
    if (tid == 0) neff[b] = (nr < KK) ? nr : KK;
}

// ===================== stage 2: feat = rt_k @ W_in + b_in via split-f16 MFMA ====
// Unfused (R5 structure); LDS tiles chunk-swizzled.
__global__ __launch_bounds__(256) void feat_mfma(
    const float* __restrict__ rt, const int* __restrict__ topidx,
    const _Float16* __restrict__ wth, const _Float16* __restrict__ wtl,
    const float* __restrict__ bin,
    _Float16* __restrict__ feath, _Float16* __restrict__ featl)
{
    const int mtile = blockIdx.x, nt = blockIdx.y;
    __shared__ _Float16 Ah[128][32], Al[128][32], Bh[128][32], Bl[128][32];
    __shared__ int tix[128];
    const int tid = threadIdx.x;
    const int w = tid >> 6, lane = tid & 63;
    const int quad = lane >> 4, l16 = lane & 15;
    const int wm = (w >> 1) * 64, wl = (w & 1) * 64;
    const int b = mtile >> 2;
    if (tid < 128) tix[tid] = topidx[mtile * 128 + tid];
    __syncthreads();
    const int arow_i = tid >> 1;              // A row this thread converts
    const int aseg = (tid & 1) * 16;          // 16-col half of that row
    const int asw = (arow_i >> 1) & 3;        // store-side swizzle for this row
    const float* arow = rt + ((size_t)b * NN + tix[arow_i]) * CC + aseg;
    _Float16* bsh = (w < 2) ? &Bh[0][0] : &Bl[0][0];
    const _Float16* bplane = (w < 2) ? wth : wtl;
    const int rowi = lane >> 2, chunk = lane & 3;
    const int ssw = (rowi >> 1) & 3;          // staging source swizzle (GLDS16)
    const int rsw = (l16 >> 1) & 3;           // read-side swizzle

    f4 acc[4][4];
    #pragma unroll
    for (int i = 0; i < 4; i++)
        #pragma unroll
        for (int j = 0; j < 4; j++)
            acc[i][j] = (f4){0.f, 0.f, 0.f, 0.f};

    for (int k0 = 0; k0 < CC; k0 += 32) {
        __syncthreads();
        // B async first (4 wave-loads per wave); source chunk pre-swizzled
        #pragma unroll
        for (int jj = 0; jj < 4; jj++) {
            int j = (w & 1) * 4 + jj;
            int row = j * 16 + rowi;
            GLDS16(bplane + (size_t)(nt * 128 + row) * CC + k0 + (chunk ^ ssw) * 8, bsh + j * 512);
        }
        // A convert (every thread); dest chunk swizzled
        {
            const float4* src = (const float4*)(arow + k0);
            #pragma unroll
            for (int c = 0; c < 2; c++) {
                float4 p = src[2 * c], q2 = src[2 * c + 1];
                float xv[8] = {p.x, p.y, p.z, p.w, q2.x, q2.y, q2.z, q2.w};
                h8 hv, lv;
                #pragma unroll
                for (int j = 0; j < 8; j++) {
                    _Float16 h = (_Float16)xv[j];
                    hv[j] = h;
                    lv[j] = (_Float16)(xv[j] - (float)h);
                }
                int ci = ((tid & 1) * 2 + c) ^ asw;
                *(h8*)&Ah[arow_i][ci * 8] = hv;
                *(h8*)&Al[arow_i][ci * 8] = lv;
            }
        }
        __syncthreads();
        h8 afh[4], afl[4], bfh[4], bfl[4];
        #pragma unroll
        for (int i = 0; i < 4; i++) {
            int ra = wm + i * 16 + l16;
            int rb = wl + i * 16 + l16;
            int qa = (quad ^ rsw) * 8;
            afh[i] = *(const h8*)&Ah[ra][qa];
            afl[i] = *(const h8*)&Al[ra][qa];
            bfh[i] = *(const h8*)&Bh[rb][qa];
            bfl[i] = *(const h8*)&Bl[rb][qa];
        }
        #pragma unroll
        for (int i = 0; i < 4; i++)
            #pragma unroll
            for (int j = 0; j < 4; j++) {
                acc[i][j] = __builtin_amdgcn_mfma_f32_16x16x32_f16(afh[i], bfh[j], acc[i][j], 0, 0, 0);
                acc[i][j] = __builtin_amdgcn_mfma_f32_16x16x32_f16(afh[i], bfl[j], acc[i][j], 0, 0, 0);
                acc[i][j] = __builtin_amdgcn_mfma_f32_16x16x32_f16(afl[i], bfh[j], acc[i][j], 0, 0, 0);
            }
    }
    #pragma unroll
    for (int j = 0; j < 4; j++) {
        int col = wl + j * 16 + l16;
        float bj = bin[nt * 128 + col];
        #pragma unroll
        for (int i = 0; i < 4; i++)
            #pragma unroll
            for (int r = 0; r < 4; r++) {
                int row = wm + i * 16 + quad * 4 + r;
                float v = acc[i][j][r] + bj;
                _Float16 h = (_Float16)v;
                size_t o = (size_t)(mtile * 128 + row) * CC + nt * 128 + col;
                feath[o] = h;
                featl[o] = (_Float16)(v - (float)h);
            }
    }
}

// ===================== stage 2b: row norms from hi/lo =====================
__global__ __launch_bounds__(256) void norm_kernel(
    const _Float16* __restrict__ feath, const _Float16* __restrict__ featl,
    float* __restrict__ normF)
{
    int r = blockIdx.x * 4 + (threadIdx.x >> 6);
    int lane = threadIdx.x & 63;
    h4 hv = ((const h4*)(feath + (size_t)r * CC))[lane];
    h4 lv = ((const h4*)(featl + (size_t)r * CC))[lane];
    float s = 0.f;
    #pragma unroll
    for (int j = 0; j < 4; j++) {
        float x = (float)hv[j] + (float)lv[j];
        s += x * x;
    }
    for (int off = 32; off; off >>= 1) s += __shfl_down(s, off);
    if (lane == 0) normF[r] = s;
}

// ===================== stage 3: fd argmin, 256x256 tile, counted-vmcnt pipeline =
// 8 waves / 512 threads (R8 showed 16 waves spills). Chunk-swizzled LDS.
__global__ __launch_bounds__(512) void argmin_mfma(
    const _Float16* __restrict__ feath, const _Float16* __restrict__ featl,
    const float* __restrict__ normF,
    const int* __restrict__ anc, const int* __restrict__ pos, const int* __restrict__ neg,
    float* __restrict__ partv, int* __restrict__ partl, float* __restrict__ partd)
{
    // bijective XCD decode: id = xcd + 8*((pr%16)*4 + s), pr = xcd*16 + ...
    const int id = blockIdx.x;
    const int xcd = id & 7, kgrp = id >> 3;
    const int pr = xcd * 16 + (kgrp >> 2);
    const int s = kgrp & 3;
    const int lt = s & 1, kt = s >> 1;
    const int t = pr >> 1, nn2 = pr & 1;
    const int a = anc[t];
    const int bb = nn2 ? neg[t] : pos[t];
    const size_t Abase = ((size_t)a * KK + kt * 256) * CC;
    const size_t Bbase = ((size_t)bb * KK + lt * 256) * CC;
    // S[buf][plane][256*32]; plane: 0=Ah 1=Al 2=Bh 3=Bl ; 128 KiB total
    __shared__ _Float16 S[2][4][8192];
    __shared__ float rdv[256][2];
    __shared__ int   rdl[256][2];
    __shared__ float rdd[256][2];
    const int tid = threadIdx.x;
    const int w = tid >> 6, lane = tid & 63;
    const int quad = lane >> 4, l16 = lane & 15;
    const int wr = w >> 1, wc = w & 1;          // wave tile: rows wr*64, cols wc*128
    const int rowi = lane >> 2, chunk = lane & 3;
    const int ssw = (rowi >> 1) & 3;            // staging source swizzle
    const int rsw = (l16 >> 1) & 3;             // read-side swizzle
    // staging role: wave w stages plane w>>1, rows (w&1)*128 .. +127
    const int plane = w >> 1;
    const int srow = (w & 1) * 128;
    const _Float16* gsrc = (plane == 0) ? feath + Abase
                         : (plane == 1) ? featl + Abase
                         : (plane == 2) ? feath + Bbase
                         :                featl + Bbase;
    const _Float16* grow = gsrc + (size_t)(srow + rowi) * CC + (chunk ^ ssw) * 8;

    f4 acc[4][8];
    #pragma unroll
    for (int i = 0; i < 4; i++)
        #pragma unroll
        for (int j = 0; j < 8; j++)
            acc[i][j] = (f4){0.f, 0.f, 0.f, 0.f};

    // prologue: stage K-step 0 into buffer 0 (8 loads/wave -> vmcnt 8)
    #pragma unroll
    for (int j = 0; j < 8; j++)
        GLDS16(grow + (size_t)(j * 16) * CC, &S[0][plane][srow * 32 + j * 512]);

    #pragma unroll
    for (int kk = 0; kk < 8; kk++) {
        const int cb = kk & 1;
        // issue next K-step's 8 loads, then wait only for the previous 8
        if (kk < 7) {
            const int k1 = (kk + 1) * 32;
            #pragma unroll
            for (int j = 0; j < 8; j++)
                GLDS16(grow + (size_t)(j * 16) * CC + k1, &S[cb ^ 1][plane][srow * 32 + j * 512]);
            asm volatile("s_waitcnt vmcnt(8)" ::: "memory");
        } else {
            asm volatile("s_waitcnt vmcnt(0)" ::: "memory");
        }
        __builtin_amdgcn_s_barrier();          // buffer cb ready for all waves
        const int qa = (quad ^ rsw) * 8;
        h8 afh[4], afl[4];
        #pragma unroll
        for (int i = 0; i < 4; i++) {
            int ra = wr * 64 + i * 16 + l16;
            afh[i] = *(const h8*)&S[cb][0][ra * 32 + qa];
            afl[i] = *(const h8*)&S[cb][1][ra * 32 + qa];
        }
        #pragma unroll
        for (int j = 0; j < 8; j++) {
            int rb = wc * 128 + j * 16 + l16;
            h8 bfh = *(const h8*)&S[cb][2][rb * 32 + qa];
            h8 bfl = *(const h8*)&S[cb][3][rb * 32 + qa];
            #pragma unroll
            for (int i = 0; i < 4; i++) {
                acc[i][j] = __builtin_amdgcn_mfma_f32_16x16x32_f16(afh[i], bfh, acc[i][j], 0, 0, 0);
                acc[i][j] = __builtin_amdgcn_mfma_f32_16x16x32_f16(afh[i], bfl, acc[i][j], 0, 0, 0);
                acc[i][j] = __builtin_amdgcn_mfma_f32_16x16x32_f16(afl[i], bfh, acc[i][j], 0, 0, 0);
            }
        }
        __builtin_amdgcn_sched_barrier(0);     // pin reads/MFMA before WAR barrier
        __builtin_amdgcn_s_barrier();          // all waves done reading buf cb
    }
    float nbj[8];
    #pragma unroll
    for (int j = 0; j < 8; j++)
        nbj[j] = normF[(size_t)bb * KK + lt * 256 + wc * 128 + j * 16 + l16];
    #pragma unroll
    for (int i = 0; i < 4; i++) {
        #pragma unroll
        for (int r = 0; r < 4; r++) {
            float bv = INFINITY; int bl = 0; float bd = 0.f;
            #pragma unroll
            for (int j = 0; j < 8; j++) {
                float d = acc[i][j][r];
                float v = nbj[j] - 2.f * d;
                int l = lt * 256 + wc * 128 + j * 16 + l16;
                if (v < bv) { bv = v; bl = l; bd = d; }
            }
            #pragma unroll
            for (int off = 1; off < 16; off <<= 1) {
                float ov = __shfl_xor(bv, off);
                int   ol = __shfl_xor(bl, off);
                float od = __shfl_xor(bd, off);
                if (ov < bv || (ov == bv && ol < bl)) { bv = ov; bl = ol; bd = od; }
            }
            if (l16 == 0) {
                int row = wr * 64 + i * 16 + quad * 4 + r;
                rdv[row][wc] = bv;
                rdl[row][wc] = bl;
                rdd[row][wc] = bd;
            }
        }
    }
    __syncthreads();
    if (tid < 256) {
        float bv = rdv[tid][0]; int bl = rdl[tid][0]; float bd = rdd[tid][0];
        float v1 = rdv[tid][1]; int l1 = rdl[tid][1];
        if (v1 < bv || (v1 == bv && l1 < bl)) { bv = v1; bl = l1; bd = rdd[tid][1]; }
        size_t idx = ((size_t)pr * KK + kt * 256 + tid) * 2 + lt;
        partv[idx] = bv; partl[idx] = bl; partd[idx] = bd;
    }
}

// ===================== stage 4: geo bitmask (argmin_fin fused) =====================
__global__ __launch_bounds__(256) void geo_kernel(
    const float* __restrict__ centk,
    const float* __restrict__ partv, const int* __restrict__ partl,
    const float* __restrict__ partd, const float* __restrict__ normF,
    const int* __restrict__ neff,
    const int* __restrict__ anc, const int* __restrict__ pos, const int* __restrict__ neg,
    float* __restrict__ sbuf, unsigned* __restrict__ gmask)
{
    const int kt = blockIdx.x;          // 0..1 (256 rows)
    const int lt4 = blockIdx.y;         // 0..3 (128 cols)
    const int pair = blockIdx.z;        // 0..127
    const int t = pair >> 1, nn2 = pair & 1;
    const int a = anc[t];
    const int bb2 = (nn2 == 0) ? pos[t] : neg[t];
    const int nea = neff[a], neb = neff[bb2];
    const bool writer = (kt == 0) && (lt4 == 0);
    __shared__ int ci[512];
    __shared__ __align__(16) float4 ca[512], cq[512];
    // fused argmin_fin: merge the 2 l-tile partials (identical tie-break order)
    for (int i = threadIdx.x; i < KK; i += 256) {
        size_t base = ((size_t)pair * KK + i) * 2;
        float bv = partv[base]; int bl = partl[base]; float bd = partd[base];
        float v = partv[base + 1]; int l = partl[base + 1];
        if (v < bv || (v == bv && l < bl)) { bv = v; bl = l; bd = partd[base + 1]; }
        ci[i] = bl;
        if (writer) {
            float na = normF[(size_t)a * KK + i];
            float nb = normF[(size_t)bb2 * KK + bl];
            float cosv = bd / (sqrtf(na) * sqrtf(nb) + 1e-8f);
            sbuf[pair * KK + i] = fmaxf(cosv, 0.f);
        }
    }
    __syncthreads();
    for (int i = threadIdx.x; i < KK; i += 256) {
        ca[i] = ((const float4*)centk)[a * KK + i];
        cq[i] = ((const float4*)centk)[bb2 * KK + ci[i]];
    }
    __syncthreads();
    const int k = kt * 256 + threadIdx.x;
    float4 pk = ca[k], qk = cq[k];
    bool rowm = k < nea;
    unsigned* outp = gmask + ((size_t)pair * KK + k) * 16 + lt4 * 4;
    for (int w = 0; w < 4; w++) {
        unsigned word = 0;
        #pragma unroll
        for (int bi = 0; bi < 32; bi++) {
            int l = lt4 * 128 + w * 32 + bi;
            float4 pl = ca[l], ql = cq[l];
            float dp2 = pk.w + pl.w - 2.f * (pk.x * pl.x + pk.y * pl.y + pk.z * pl.z);
            float dp = sqrtf(fmaxf(dp2, 0.f) + 1e-12f);
            float dq2 = qk.w + ql.w - 2.f * (qk.x * ql.x + qk.y * ql.y + qk.z * ql.z);
            float dq = sqrtf(fmaxf(dq2, 0.f) + 1e-12f);
            bool g = (fabsf(dp - dq) < 0.5f) && rowm && (l < neb) && (l != k);
            word |= (g ? (1u << bi) : 0u);
        }
        outp[w] = word;
    }
}

// ===================== stage 5: power iteration + sort + MLP (merged, R5) ======
__global__ __launch_bounds__(1024, 4) void power_kernel(
    const unsigned* __restrict__ gmask, const float* __restrict__ sbuf,
    const int* __restrict__ neff,
    const int* __restrict__ anc, const int* __restrict__ pos, const int* __restrict__ neg,
    const float* __restrict__ W1, const float* __restrict__ b1,
    const float* __restrict__ W2, const float* __restrict__ b2,
    float* __restrict__ out)
{
    const int pair = blockIdx.x;
    const int tid = threadIdx.x;
    const int row = tid & 511;
    const int half = tid >> 9;
    const int tt = pair >> 1, nn2 = pair & 1;
    const int a = anc[tt];
    const int bb2 = (nn2 == 0) ? pos[tt] : neg[tt];
    const int nea = neff[a], neb = neff[bb2];
    __shared__ __align__(16) float uu[512];    // split layout, see UADDR
    __shared__ float T[64][257];
    __shared__ float pacc[1024];
    __shared__ float red[16];
    __shared__ float ev[512];
    __shared__ float hpart[1024];
    __shared__ int convflag;
    unsigned m[8];
    const unsigned* g = gmask + ((size_t)pair * KK + row) * 16 + half * 8;
    #pragma unroll
    for (int w = 0; w < 8; w++) m[w] = g[w];
    const float s = sbuf[pair * KK + row];
    // wave-uniform activity: this wave's 64-row span entirely >= nea -> skip
    const int wbase = tid & 511 & ~63;
    const bool wact = (wbase < nea);
    // block-uniform: number of nonzero 32-col words in this half
    int nw = (neb - half * 256 + 31) >> 5;
    nw = (nw < 0) ? 0 : (nw > 8 ? 8 : nw);
    const int bp = tid & 63;
    const int vh = tid >> 6;
    // split-u address: read side lane bp reads uu[4*bp..+3] and uu[256+4*bp..+3]
    // -> stride-16B ds_read_b128, conflict-free.
    #define UADDR(r) ((((r) & 4) << 6) + (((r) >> 3) << 2) + ((r) & 3))
    const int GV_[16] = {0,1,3,2,6,7,5,4,12,13,15,14,10,11,9,8};
    const int GB[15] = {0,1,0,2,0,1,0,3,0,1,0,2,0,1,0};
    const float GS[15] = {1.f,1.f,-1.f,1.f,1.f,-1.f,-1.f,1.f,1.f,1.f,-1.f,-1.f,1.f,-1.f,-1.f};
    float v = 0.044194173824159216f;   // 1/sqrt(512)
    float vnprev = v;                  // previous NORMALIZED v
    if (half == 0) uu[UADDR(row)] = s * v;
    __syncthreads();
    for (int it = 0; it < 20; it++) {
        {
            float4 ulo = *(const float4*)&uu[bp * 4];
            float4 uhi = *(const float4*)&uu[256 + bp * 4];
            float ul[4] = {ulo.x, ulo.y, ulo.z, ulo.w};
            float H = 0.f;
            H += (float)((vh >> 0) & 1) * uhi.x;
            H += (float)((vh >> 1) & 1) * uhi.y;
            H += (float)((vh >> 2) & 1) * uhi.z;
            H += (float)((vh >> 3) & 1) * uhi.w;
            float L = 0.f;
            T[bp][vh * 16 + 0] = H;
            #pragma unroll
            for (int k = 1; k < 16; k++) {
                L += GS[k - 1] * ul[GB[k - 1]];
                T[bp][vh * 16 + GV_[k]] = H + L;
            }
        }
        __syncthreads();
        float a0 = 0.f, a1 = 0.f, a2 = 0.f, a3 = 0.f;
        if (wact) {
            #define GATHERW(w)  do { unsigned mw = m[w]; \
                const int p0 = half * 32 + (w) * 4; \
                a0 += T[p0 + 0][mw & 255u]; \
                a1 += T[p0 + 1][(mw >> 8) & 255u]; \
                a2 += T[p0 + 2][(mw >> 16) & 255u]; \
                a3 += T[p0 + 3][mw >> 24]; } while (0)
            if (nw > 0) GATHERW(0);
            if (nw > 1) GATHERW(1);
            if (nw > 2) GATHERW(2);
            if (nw > 3) GATHERW(3);
            if (nw > 4) GATHERW(4);
            if (nw > 5) GATHERW(5);
            if (nw > 6) GATHERW(6);
            if (nw > 7) GATHERW(7);
            #undef GATHERW
        }
        pacc[tid] = (a0 + a1) + (a2 + a3);
        __syncthreads();
        float wk = s * (pacc[row] + pacc[row + 512]);
        if ((it & 3) == 3) {
            // full normalization (exact reference formula)
            float t2 = wk * wk;
            for (int off = 32; off; off >>= 1) t2 += __shfl_down(t2, off);
            if ((tid & 63) == 0) red[tid >> 6] = t2;
            if (tid == 0) convflag = 1;
            __syncthreads();
            float tot = 0.f;
            #pragma unroll
            for (int x = 0; x < 16; x++) tot += red[x];
            tot *= 0.5f;
            v = wk / (sqrtf(tot) + 1e-8f);
            bool eq = (__float_as_uint(v) == __float_as_uint(vnprev));
            vnprev = v;
            if (half == 0) uu[UADDR(row)] = s * v;
            if (!eq) convflag = 0;
            __syncthreads();
            if (convflag) break;   // bitwise fixed point: remaining iters identity
        } else {
            // deferred: direction-only update (linear iteration)
            if (half == 0) uu[UADDR(row)] = s * wk;
            __syncthreads();
        }
    }
    if (half == 0) ev[row] = v;
    __syncthreads();
    for (int kk = 2; kk <= 512; kk <<= 1) {
        for (int j = kk >> 1; j; j >>= 1) {
            if (tid < 256) {
                int i = ((tid & ~(j - 1)) << 1) | (tid & (j - 1));
                int p = i | j;
                float x = ev[i], y = ev[p];
                bool up = (i & kk) == 0;
                if (up ? (x < y) : (x > y)) { ev[i] = y; ev[p] = x; }
            }
            __syncthreads();
        }
    }
    const int cbase = half * 256;
    float h = (half == 0) ? b1[row] : 0.f;
    #pragma unroll 8
    for (int l = 0; l < 256; l++)
        h += ev[cbase + l] * W1[(size_t)(cbase + l) * KK + row];
    hpart[tid] = h;
    __syncthreads();
    float term = 0.f;
    if (half == 0) {
        float hv = fmaxf(hpart[row] + hpart[row + 512], 0.f);
        term = hv * W2[row];
    }
    for (int off = 32; off; off >>= 1) term += __shfl_down(term, off);
    if ((tid & 63) == 0) red[tid >> 6] = term;
    __syncthreads();
    if (tid == 0) {
        float sc = 0.f;
        #pragma unroll
        for (int x = 0; x < 16; x++) sc += red[x];
        sc += b2[0];
        out[pair] = 1.f / (1.f + expf(-sc));
        out[NPAIR + pair] = (pair & 1) ? 0.f : 1.f;
    }
}

extern "C" void kernel_launch(void* const* d_in, const int* in_sizes, int n_in,
                              void* d_out, int out_size, void* d_ws, size_t ws_size,
                              hipStream_t stream) {
    (void)in_sizes; (void)n_in; (void)out_size; (void)ws_size;
    const float* rt    = (const float*)d_in[0];
    const float* cents = (const float*)d_in[1];
    const float* attn  = (const float*)d_in[2];
    const float* sas   = (const float*)d_in[3];
    const int* num_rt  = (const int*)d_in[4];
    const int* anc     = (const int*)d_in[5];
    const int* pos     = (const int*)d_in[6];
    const int* neg     = (const int*)d_in[7];
    const float* Win   = (const float*)d_in[8];
    const float* bin   = (const float*)d_in[9];
    const float* W1    = (const float*)d_in[10];
    const float* b1    = (const float*)d_in[11];
    const float* W2    = (const float*)d_in[12];
    const float* b2    = (const float*)d_in[13];

    float* ws = (float*)d_ws;
    _Float16* feath = (_Float16*)ws;
    _Float16* featl = (_Float16*)(ws + 4194304);
    float* normF = ws + 8388608;
    float* centk = ws + 8421376;
    float* sbuf  = ws + 8552448;
    int* topidx  = (int*)(ws + 8617984);
    int* neffp   = (int*)(ws + 8650752);
    unsigned* gmask = (unsigned*)(ws + 8716352);
    _Float16* wth = (_Float16*)(ws + 8716352 + 786432);
    _Float16* wtl = (_Float16*)(ws + 8716352 + 819200);
    float* partv = (float*)(ws + 9764928);
    int*   partl = (int*)(ws + 10027072);
    float* partd = (float*)(ws + 10289216);
    float* out = (float*)d_out;

    wtrans_kernel<<<dim3(4, 4), 256, 0, stream>>>(Win, wth, wtl);
    sel_kernel<<<64, 512, 0, stream>>>(attn, cents, sas, num_rt, topidx, neffp, centk);
    feat_mfma<<<dim3(256, 2), 256, 0, stream>>>(rt, topidx, wth, wtl, bin, feath, featl);
    norm_kernel<<<8192, 256, 0, stream>>>(feath, featl, normF);
    argmin_mfma<<<512, 512, 0, stream>>>(feath, featl, normF, anc, pos, neg, partv, partl, partd);
    geo_kernel<<<dim3(2, 4, 128), 256, 0, stream>>>(centk, partv, partl, partd, normF, neffp, anc, pos, neg, sbuf, gmask);
    power_kernel<<<128, 1024, 0, stream>>>(gmask, sbuf, neffp, anc, pos, neg, W1, b1, W2, b2, out);
}

// Round 10
// 331.845 us; speedup vs baseline: 1.1536x; 1.0327x over previous
//
#include <hip/hip_runtime.h>
#include <cstddef>

#define BB 64
#define NN 1024
#define CC 256
#define KK 512
#define TT 64
#define NPAIR 128

typedef _Float16 h8 __attribute__((ext_vector_type(8)));
typedef _Float16 h4 __attribute__((ext_vector_type(4)));
typedef float f4 __attribute__((ext_vector_type(4)));

// async global->LDS, 16B per lane; LDS dest = wave-uniform base + lane*16
typedef __attribute__((address_space(1))) const void GV;
typedef __attribute__((address_space(3))) void LV;
#define GLDS16(g, s) __builtin_amdgcn_global_load_lds((GV*)(const void*)(g), (LV*)(void*)(s), 16, 0, 0)

// ---------------- ws layout (float words) ----------------
// feath   : 0          size 4194304  (8388608 f16: 32768 x 256 hi)
// featl   : 4194304    size 4194304  (lo plane)
// normF   : 8388608    size 32768
// centk   : 8421376    size B*K*4   = 131072   (x,y,z,|c|^2)
// sbuf    : 8552448    size 65536   (T*2*K)
// topidx  : 8617984    size 32768   (int)
// neff    : 8650752    size 64      (int)
// gmask   : 8716352    size NPAIR*K*16 = 1048576 (uint)
//   wth/wtl alias gmask top (+786432 / +819200) - consumed by feat before geo
// partv   : 9764928    size 131072 (2-way partials)
// partl   : 10027072
// partd   : 10289216
// total 10551360 words = 42.2 MB
//
// LDS chunk swizzle (argmin/feat tiles): chunk c -> c ^ ((row>>1)&3), applied
// both staging-side and read-side. Verified R7: conflicts 3.16M -> 12K.
// R8 lesson: 1024-thread argmin spills (<=128 regs) -> stay 512 thr / 8 waves.

// ===================== stage 0+1: W_in transpose/split + selection (fused) =====
__global__ __launch_bounds__(512) void prep_kernel(
    const float* __restrict__ Win, _Float16* __restrict__ wth, _Float16* __restrict__ wtl,
    const float* __restrict__ attn, const float* __restrict__ cents,
    const float* __restrict__ sas, const int* __restrict__ num_rt,
    int* __restrict__ topidx, int* __restrict__ neff, float* __restrict__ centk)
{
    if (blockIdx.x < 16) {
        // ---- wtrans tile (block-uniform branch; barriers legal) ----
        __shared__ float t[64][65];
        const int k0 = (blockIdx.x & 3) * 64, n0 = ((int)blockIdx.x >> 2) * 64;
        const int tid = threadIdx.x;
        const int c = tid & 63, r0 = tid >> 6;          // 0..7
        for (int r = r0; r < 64; r += 8)
            t[r][c] = Win[(size_t)(k0 + r) * CC + n0 + c];
        __syncthreads();
        for (int r = r0; r < 64; r += 8) {
            float x = t[c][r];                           // x = Win[k0+c][n0+r]
            _Float16 h = (_Float16)x;
            size_t o = (size_t)(n0 + r) * CC + k0 + c;
            wth[o] = h;
            wtl[o] = (_Float16)(x - (float)h);
        }
        return;
    }
    // ---- selection for batch b ----
    __shared__ unsigned long long keys[1024];
    const int b = blockIdx.x - 16, tid = threadIdx.x;
    const int nr = num_rt[b];
    for (int i = tid; i < 1024; i += 512) {
        float a = (i < nr) ? attn[b * NN + i] : -1e9f;
        unsigned u = __float_as_uint(a);
        u = (u & 0x80000000u) ? ~u : (u | 0x80000000u);
        keys[i] = ((unsigned long long)u << 32) | (unsigned)(0xFFFFFFFFu - (unsigned)i);
    }
    __syncthreads();
    for (int k = 2; k <= 1024; k <<= 1) {
        for (int j = k >> 1; j > 0; j >>= 1) {
            int i = ((tid & ~(j - 1)) << 1) | (tid & (j - 1));
            int p = i | j;
            unsigned long long a = keys[i], c = keys[p];
            bool up = (i & k) == 0;
            if (up ? (a < c) : (a > c)) { keys[i] = c; keys[p] = a; }
            __syncthreads();
        }
    }
    {
        unsigned long long key = keys[tid];
        int idx = (int)(~(unsigned)key);
        float x = cents[(b * NN + idx) * 3 + 0];
        float y = cents[(b * NN + idx) * 3 + 1];
        float z = cents[(b * NN + idx) * 3 + 2];
        if (idx < nr) {
            float sc = sas[b * 4 + 3];
            x = x * sc + sas[b * 4 + 0];
            y = y * sc + sas[b * 4 + 1];
            z = z * sc + sas[b * 4 + 2];
        }
        float nc = x * x + y * y + z * z;
        ((float4*)centk)[b * KK + tid] = make_float4(x, y, z, nc);
        topidx[b * KK + tid] = idx;
    }
    if (tid == 0) neff[b] = (nr < KK) ? nr : KK;
}

// ===================== stage 2: feat = rt_k @ W_in + b_in via split-f16 MFMA ====
__global__ __launch_bounds__(256) void feat_mfma(
    const float* __restrict__ rt, const int* __restrict__ topidx,
    const _Float16* __restrict__ wth, const _Float16* __restrict__ wtl,
    const float* __restrict__ bin,
    _Float16* __restrict__ feath, _Float16* __restrict__ featl)
{
    const int mtile = blockIdx.x, nt = blockIdx.y;
    __shared__ _Float16 Ah[128][32], Al[128][32], Bh[128][32], Bl[128][32];
    __shared__ int tix[128];
    const int tid = threadIdx.x;
    const int w = tid >> 6, lane = tid & 63;
    const int quad = lane >> 4, l16 = lane & 15;
    const int wm = (w >> 1) * 64, wl = (w & 1) * 64;
    const int b = mtile >> 2;
    if (tid < 128) tix[tid] = topidx[mtile * 128 + tid];
    __syncthreads();
    const int arow_i = tid >> 1;              // A row this thread converts
    const int aseg = (tid & 1) * 16;          // 16-col half of that row
    const int asw = (arow_i >> 1) & 3;        // store-side swizzle for this row
    const float* arow = rt + ((size_t)b * NN + tix[arow_i]) * CC + aseg;
    _Float16* bsh = (w < 2) ? &Bh[0][0] : &Bl[0][0];
    const _Float16* bplane = (w < 2) ? wth : wtl;
    const int rowi = lane >> 2, chunk = lane & 3;
    const int ssw = (rowi >> 1) & 3;          // staging source swizzle (GLDS16)
    const int rsw = (l16 >> 1) & 3;           // read-side swizzle

    f4 acc[4][4];
    #pragma unroll
    for (int i = 0; i < 4; i++)
        #pragma unroll
        for (int j = 0; j < 4; j++)
            acc[i][j] = (f4){0.f, 0.f, 0.f, 0.f};

    for (int k0 = 0; k0 < CC; k0 += 32) {
        __syncthreads();
        // B async first (4 wave-loads per wave); source chunk pre-swizzled
        #pragma unroll
        for (int jj = 0; jj < 4; jj++) {
            int j = (w & 1) * 4 + jj;
            int row = j * 16 + rowi;
            GLDS16(bplane + (size_t)(nt * 128 + row) * CC + k0 + (chunk ^ ssw) * 8, bsh + j * 512);
        }
        // A convert (every thread); dest chunk swizzled
        {
            const float4* src = (const float4*)(arow + k0);
            #pragma unroll
            for (int c = 0; c < 2; c++) {
                float4 p = src[2 * c], q2 = src[2 * c + 1];
                float xv[8] = {p.x, p.y, p.z, p.w, q2.x, q2.y, q2.z, q2.w};
                h8 hv, lv;
                #pragma unroll
                for (int j = 0; j < 8; j++) {
                    _Float16 h = (_Float16)xv[j];
                    hv[j] = h;
                    lv[j] = (_Float16)(xv[j] - (float)h);
                }
                int ci = ((tid & 1) * 2 + c) ^ asw;
                *(h8*)&Ah[arow_i][ci * 8] = hv;
                *(h8*)&Al[arow_i][ci * 8] = lv;
            }
        }
        __syncthreads();
        h8 afh[4], afl[4], bfh[4], bfl[4];
        #pragma unroll
        for (int i = 0; i < 4; i++) {
            int ra = wm + i * 16 + l16;
            int rb = wl + i * 16 + l16;
            int qa = (quad ^ rsw) * 8;
            afh[i] = *(const h8*)&Ah[ra][qa];
            afl[i] = *(const h8*)&Al[ra][qa];
            bfh[i] = *(const h8*)&Bh[rb][qa];
            bfl[i] = *(const h8*)&Bl[rb][qa];
        }
        #pragma unroll
        for (int i = 0; i < 4; i++)
            #pragma unroll
            for (int j = 0; j < 4; j++) {
                acc[i][j] = __builtin_amdgcn_mfma_f32_16x16x32_f16(afh[i], bfh[j], acc[i][j], 0, 0, 0);
                acc[i][j] = __builtin_amdgcn_mfma_f32_16x16x32_f16(afh[i], bfl[j], acc[i][j], 0, 0, 0);
                acc[i][j] = __builtin_amdgcn_mfma_f32_16x16x32_f16(afl[i], bfh[j], acc[i][j], 0, 0, 0);
            }
    }
    #pragma unroll
    for (int j = 0; j < 4; j++) {
        int col = wl + j * 16 + l16;
        float bj = bin[nt * 128 + col];
        #pragma unroll
        for (int i = 0; i < 4; i++)
            #pragma unroll
            for (int r = 0; r < 4; r++) {
                int row = wm + i * 16 + quad * 4 + r;
                float v = acc[i][j][r] + bj;
                _Float16 h = (_Float16)v;
                size_t o = (size_t)(mtile * 128 + row) * CC + nt * 128 + col;
                feath[o] = h;
                featl[o] = (_Float16)(v - (float)h);
            }
    }
}

// ===================== stage 2b: row norms from hi/lo (grid-stride) ============
__global__ __launch_bounds__(256) void norm_kernel(
    const _Float16* __restrict__ feath, const _Float16* __restrict__ featl,
    float* __restrict__ normF)
{
    const int w = threadIdx.x >> 6;
    const int lane = threadIdx.x & 63;
    for (int base = blockIdx.x; base < 8192; base += 2048) {
        int r = base * 4 + w;
        h4 hv = ((const h4*)(feath + (size_t)r * CC))[lane];
        h4 lv = ((const h4*)(featl + (size_t)r * CC))[lane];
        float s = 0.f;
        #pragma unroll
        for (int j = 0; j < 4; j++) {
            float x = (float)hv[j] + (float)lv[j];
            s += x * x;
        }
        for (int off = 32; off; off >>= 1) s += __shfl_down(s, off);
        if (lane == 0) normF[r] = s;
    }
}

// ===================== stage 3: fd argmin, 256x256 tile, 2-phase interleave =====
// v10: each K-step split into two phases {issue 4 gloads | ds_read B-cluster
// interleaved with 48 MFMA under setprio}; vmcnt(4) counts 8-old + 4-new
// outstanding -> <=4 means old buffer fully landed. 3 barriers/K-step. Buffer
// discipline identical to the proven 2-buffer loop -> race-safe; MFMA order
// per acc cell unchanged -> bit-exact. Chunk-swizzled LDS (R7).
__global__ __launch_bounds__(512) void argmin_mfma(
    const _Float16* __restrict__ feath, const _Float16* __restrict__ featl,
    const float* __restrict__ normF,
    const int* __restrict__ anc, const int* __restrict__ pos, const int* __restrict__ neg,
    float* __restrict__ partv, int* __restrict__ partl, float* __restrict__ partd)
{
    // bijective XCD decode: id = xcd + 8*((pr%16)*4 + s), pr = xcd*16 + ...
    const int id = blockIdx.x;
    const int xcd = id & 7, kgrp = id >> 3;
    const int pr = xcd * 16 + (kgrp >> 2);
    const int s = kgrp & 3;
    const int lt = s & 1, kt = s >> 1;
    const int t = pr >> 1, nn2 = pr & 1;
    const int a = anc[t];
    const int bb = nn2 ? neg[t] : pos[t];
    const size_t Abase = ((size_t)a * KK + kt * 256) * CC;
    const size_t Bbase = ((size_t)bb * KK + lt * 256) * CC;
    // S[buf][plane][256*32]; plane: 0=Ah 1=Al 2=Bh 3=Bl ; 128 KiB total
    __shared__ _Float16 S[2][4][8192];
    __shared__ float rdv[256][2];
    __shared__ int   rdl[256][2];
    __shared__ float rdd[256][2];
    const int tid = threadIdx.x;
    const int w = tid >> 6, lane = tid & 63;
    const int quad = lane >> 4, l16 = lane & 15;
    const int wr = w >> 1, wc = w & 1;          // wave tile: rows wr*64, cols wc*128
    const int rowi = lane >> 2, chunk = lane & 3;
    const int ssw = (rowi >> 1) & 3;            // staging source swizzle
    const int rsw = (l16 >> 1) & 3;             // read-side swizzle
    // staging role: wave w stages plane w>>1, rows (w&1)*128 .. +127
    const int plane = w >> 1;
    const int srow = (w & 1) * 128;
    const _Float16* gsrc = (plane == 0) ? feath + Abase
                         : (plane == 1) ? featl + Abase
                         : (plane == 2) ? feath + Bbase
                         :                featl + Bbase;
    const _Float16* grow = gsrc + (size_t)(srow + rowi) * CC + (chunk ^ ssw) * 8;

    f4 acc[4][8];
    #pragma unroll
    for (int i = 0; i < 4; i++)
        #pragma unroll
        for (int j = 0; j < 8; j++)
            acc[i][j] = (f4){0.f, 0.f, 0.f, 0.f};

    // prologue: stage K-step 0 into buffer 0 (8 loads/wave)
    #pragma unroll
    for (int j = 0; j < 8; j++)
        GLDS16(grow + (size_t)(j * 16) * CC, &S[0][plane][srow * 32 + j * 512]);

    #pragma unroll
    for (int kk = 0; kk < 8; kk++) {
        const int cb = kk & 1;
        // ---- phase A: issue first half of next-step loads, drain prev step ----
        if (kk < 7) {
            const int k1 = (kk + 1) * 32;
            #pragma unroll
            for (int j = 0; j < 4; j++)
                GLDS16(grow + (size_t)(j * 16) * CC + k1, &S[cb ^ 1][plane][srow * 32 + j * 512]);
            asm volatile("s_waitcnt vmcnt(4)" ::: "memory");   // 8 old + 4 new -> old done
        } else {
            asm volatile("s_waitcnt vmcnt(0)" ::: "memory");
        }
        __builtin_amdgcn_s_barrier();          // buffer cb fully staged for all waves
        const int qa = (quad ^ rsw) * 8;
        h8 afh[4], afl[4];
        #pragma unroll
        for (int i = 0; i < 4; i++) {
            int ra = wr * 64 + i * 16 + l16;
            afh[i] = *(const h8*)&S[cb][0][ra * 32 + qa];
            afl[i] = *(const h8*)&S[cb][1][ra * 32 + qa];
        }
        __builtin_amdgcn_s_setprio(1);
        #pragma unroll
        for (int j = 0; j < 4; j++) {
            int rb = wc * 128 + j * 16 + l16;
            h8 bfh = *(const h8*)&S[cb][2][rb * 32 + qa];
            h8 bfl = *(const h8*)&S[cb][3][rb * 32 + qa];
            #pragma unroll
            for (int i = 0; i < 4; i++) {
                acc[i][j] = __builtin_amdgcn_mfma_f32_16x16x32_f16(afh[i], bfh, acc[i][j], 0, 0, 0);
                acc[i][j] = __builtin_amdgcn_mfma_f32_16x16x32_f16(afh[i], bfl, acc[i][j], 0, 0, 0);
                acc[i][j] = __builtin_amdgcn_mfma_f32_16x16x32_f16(afl[i], bfh, acc[i][j], 0, 0, 0);
            }
        }
        __builtin_amdgcn_s_setprio(0);
        __builtin_amdgcn_sched_barrier(0);
        __builtin_amdgcn_s_barrier();          // phase alignment (role split)
        // ---- phase B: issue second half of next-step loads, compute j=4..7 ----
        if (kk < 7) {
            const int k1 = (kk + 1) * 32;
            #pragma unroll
            for (int j = 4; j < 8; j++)
                GLDS16(grow + (size_t)(j * 16) * CC + k1, &S[cb ^ 1][plane][srow * 32 + j * 512]);
        }
        __builtin_amdgcn_s_setprio(1);
        #pragma unroll
        for (int j = 4; j < 8; j++) {
            int rb = wc * 128 + j * 16 + l16;
            h8 bfh = *(const h8*)&S[cb][2][rb * 32 + qa];
            h8 bfl = *(const h8*)&S[cb][3][rb * 32 + qa];
            #pragma unroll
            for (int i = 0; i < 4; i++) {
                acc[i][j] = __builtin_amdgcn_mfma_f32_16x16x32_f16(afh[i], bfh, acc[i][j], 0, 0, 0);
                acc[i][j] = __builtin_amdgcn_mfma_f32_16x16x32_f16(afh[i], bfl, acc[i][j], 0, 0, 0);
                acc[i][j] = __builtin_amdgcn_mfma_f32_16x16x32_f16(afl[i], bfh, acc[i][j], 0, 0, 0);
            }
        }
        __builtin_amdgcn_s_setprio(0);
        __builtin_amdgcn_sched_barrier(0);
        __builtin_amdgcn_s_barrier();          // WAR: all waves done reading cb
    }
    float nbj[8];
    #pragma unroll
    for (int j = 0; j < 8; j++)
        nbj[j] = normF[(size_t)bb * KK + lt * 256 + wc * 128 + j * 16 + l16];
    #pragma unroll
    for (int i = 0; i < 4; i++) {
        #pragma unroll
        for (int r = 0; r < 4; r++) {
            float bv = INFINITY; int bl = 0; float bd = 0.f;
            #pragma unroll
            for (int j = 0; j < 8; j++) {
                float d = acc[i][j][r];
                float v = nbj[j] - 2.f * d;
                int l = lt * 256 + wc * 128 + j * 16 + l16;
                if (v < bv) { bv = v; bl = l; bd = d; }
            }
            #pragma unroll
            for (int off = 1; off < 16; off <<= 1) {
                float ov = __shfl_xor(bv, off);
                int   ol = __shfl_xor(bl, off);
                float od = __shfl_xor(bd, off);
                if (ov < bv || (ov == bv && ol < bl)) { bv = ov; bl = ol; bd = od; }
            }
            if (l16 == 0) {
                int row = wr * 64 + i * 16 + quad * 4 + r;
                rdv[row][wc] = bv;
                rdl[row][wc] = bl;
                rdd[row][wc] = bd;
            }
        }
    }
    __syncthreads();
    if (tid < 256) {
        float bv = rdv[tid][0]; int bl = rdl[tid][0]; float bd = rdd[tid][0];
        float v1 = rdv[tid][1]; int l1 = rdl[tid][1];
        if (v1 < bv || (v1 == bv && l1 < bl)) { bv = v1; bl = l1; bd = rdd[tid][1]; }
        size_t idx = ((size_t)pr * KK + kt * 256 + tid) * 2 + lt;
        partv[idx] = bv; partl[idx] = bl; partd[idx] = bd;
    }
}

// ===================== stage 4: geo bitmask (argmin_fin fused) =====================
__global__ __launch_bounds__(256) void geo_kernel(
    const float* __restrict__ centk,
    const float* __restrict__ partv, const int* __restrict__ partl,
    const float* __restrict__ partd, const float* __restrict__ normF,
    const int* __restrict__ neff,
    const int* __restrict__ anc, const int* __restrict__ pos, const int* __restrict__ neg,
    float* __restrict__ sbuf, unsigned* __restrict__ gmask)
{
    const int kt = blockIdx.x;          // 0..1 (256 rows)
    const int lt4 = blockIdx.y;         // 0..3 (128 cols)
    const int pair = blockIdx.z;        // 0..127
    const int t = pair >> 1, nn2 = pair & 1;
    const int a = anc[t];
    const int bb2 = (nn2 == 0) ? pos[t] : neg[t];
    const int nea = neff[a], neb = neff[bb2];
    const bool writer = (kt == 0) && (lt4 == 0);
    __shared__ int ci[512];
    __shared__ __align__(16) float4 ca[512], cq[512];
    // fused argmin_fin: merge the 2 l-tile partials (identical tie-break order)
    for (int i = threadIdx.x; i < KK; i += 256) {
        size_t base = ((size_t)pair * KK + i) * 2;
        float bv = partv[base]; int bl = partl[base]; float bd = partd[base];
        float v = partv[base + 1]; int l = partl[base + 1];
        if (v < bv || (v == bv && l < bl)) { bv = v; bl = l; bd = partd[base + 1]; }
        ci[i] = bl;
        if (writer) {
            float na = normF[(size_t)a * KK + i];
            float nb = normF[(size_t)bb2 * KK + bl];
            float cosv = bd / (sqrtf(na) * sqrtf(nb) + 1e-8f);
            sbuf[pair * KK + i] = fmaxf(cosv, 0.f);
        }
    }
    __syncthreads();
    for (int i = threadIdx.x; i < KK; i += 256) {
        ca[i] = ((const float4*)centk)[a * KK + i];
        cq[i] = ((const float4*)centk)[bb2 * KK + ci[i]];
    }
    __syncthreads();
    const int k = kt * 256 + threadIdx.x;
    float4 pk = ca[k], qk = cq[k];
    bool rowm = k < nea;
    unsigned* outp = gmask + ((size_t)pair * KK + k) * 16 + lt4 * 4;
    for (int w = 0; w < 4; w++) {
        unsigned word = 0;
        #pragma unroll
        for (int bi = 0; bi < 32; bi++) {
            int l = lt4 * 128 + w * 32 + bi;
            float4 pl = ca[l], ql = cq[l];
            float dp2 = pk.w + pl.w - 2.f * (pk.x * pl.x + pk.y * pl.y + pk.z * pl.z);
            float dp = sqrtf(fmaxf(dp2, 0.f) + 1e-12f);
            float dq2 = qk.w + ql.w - 2.f * (qk.x * ql.x + qk.y * ql.y + qk.z * ql.z);
            float dq = sqrtf(fmaxf(dq2, 0.f) + 1e-12f);
            bool g = (fabsf(dp - dq) < 0.5f) && rowm && (l < neb) && (l != k);
            word |= (g ? (1u << bi) : 0u);
        }
        outp[w] = word;
    }
}

// ===================== stage 5: power iteration + sort + MLP (512 thr) =========
// v10: 512 threads, each owning a FULL row (16 mask words in two guarded
// 8-word groups, identical summation tree to the old half-split) -> no pacc
// round-trip, one barrier fewer per iteration. T-build covers 2 stripes per
// thread (bit-identical per-stripe). Norm total = sum of 8 wave partials
// (old: 16 duplicated partials x 0.5 -- tolerance-trivial change). Keeps
// UADDR split-u, deferred normalization, bitwise fixed-point early exit.
__global__ __launch_bounds__(512, 2) void power_kernel(
    const unsigned* __restrict__ gmask, const float* __restrict__ sbuf,
    const int* __restrict__ neff,
    const int* __restrict__ anc, const int* __restrict__ pos, const int* __restrict__ neg,
    const float* __restrict__ W1, const float* __restrict__ b1,
    const float* __restrict__ W2, const float* __restrict__ b2,
    float* __restrict__ out)
{
    const int pair = blockIdx.x;
    const int tid = threadIdx.x;
    const int row = tid;               // 0..511
    const int tt = pair >> 1, nn2 = pair & 1;
    const int a = anc[tt];
    const int bb2 = (nn2 == 0) ? pos[tt] : neg[tt];
    const int nea = neff[a], neb = neff[bb2];
    __shared__ __align__(16) float uu[512];    // split layout, see UADDR
    __shared__ float T[64][257];
    __shared__ float red[16];
    __shared__ float ev[512];
    __shared__ int convflag;
    unsigned m[16];
    const unsigned* g = gmask + ((size_t)pair * KK + row) * 16;
    #pragma unroll
    for (int w = 0; w < 16; w++) m[w] = g[w];
    const float s = sbuf[pair * KK + row];
    // wave-uniform activity: this wave's 64-row span entirely >= nea -> skip
    const int wbase = tid & ~63;
    const bool wact = (wbase < nea);
    // block-uniform word bounds per half
    int nw0 = (neb + 31) >> 5;               nw0 = (nw0 < 0) ? 0 : (nw0 > 8 ? 8 : nw0);
    int nw1 = (neb - 256 + 31) >> 5;         nw1 = (nw1 < 0) ? 0 : (nw1 > 8 ? 8 : nw1);
    const int bp = tid & 63;
    const int vh = tid >> 6;                 // 0..7 (stripes vh and vh+8)
    #define UADDR(r) ((((r) & 4) << 6) + (((r) >> 3) << 2) + ((r) & 3))
    const int GV_[16] = {0,1,3,2,6,7,5,4,12,13,15,14,10,11,9,8};
    const int GB[15] = {0,1,0,2,0,1,0,3,0,1,0,2,0,1,0};
    const float GS[15] = {1.f,1.f,-1.f,1.f,1.f,-1.f,-1.f,1.f,1.f,1.f,-1.f,-1.f,1.f,-1.f,-1.f};
    float v = 0.044194173824159216f;   // 1/sqrt(512)
    float vnprev = v;                  // previous NORMALIZED v
    uu[UADDR(row)] = s * v;
    __syncthreads();
    for (int it = 0; it < 20; it++) {
        {
            float4 ulo = *(const float4*)&uu[bp * 4];
            float4 uhi = *(const float4*)&uu[256 + bp * 4];
            float ul[4] = {ulo.x, ulo.y, ulo.z, ulo.w};
            #pragma unroll
            for (int sp = 0; sp < 2; sp++) {
                const int s8 = vh + sp * 8;
                float H = 0.f;
                H += (float)((s8 >> 0) & 1) * uhi.x;
                H += (float)((s8 >> 1) & 1) * uhi.y;
                H += (float)((s8 >> 2) & 1) * uhi.z;
                H += (float)((s8 >> 3) & 1) * uhi.w;
                float L = 0.f;
                T[bp][s8 * 16 + 0] = H;
                #pragma unroll
                for (int k = 1; k < 16; k++) {
                    L += GS[k - 1] * ul[GB[k - 1]];
                    T[bp][s8 * 16 + GV_[k]] = H + L;
                }
            }
        }
        __syncthreads();
        float a0 = 0.f, a1 = 0.f, a2 = 0.f, a3 = 0.f;
        float c0 = 0.f, c1 = 0.f, c2 = 0.f, c3 = 0.f;
        if (wact) {
            #define GATHERW(w, p0, A0, A1, A2, A3)  do { unsigned mw = m[w]; \
                A0 += T[(p0) + 0][mw & 255u]; \
                A1 += T[(p0) + 1][(mw >> 8) & 255u]; \
                A2 += T[(p0) + 2][(mw >> 16) & 255u]; \
                A3 += T[(p0) + 3][mw >> 24]; } while (0)
            if (nw0 > 0) GATHERW(0, 0, a0, a1, a2, a3);
            if (nw0 > 1) GATHERW(1, 4, a0, a1, a2, a3);
            if (nw0 > 2) GATHERW(2, 8, a0, a1, a2, a3);
            if (nw0 > 3) GATHERW(3, 12, a0, a1, a2, a3);
            if (nw0 > 4) GATHERW(4, 16, a0, a1, a2, a3);
            if (nw0 > 5) GATHERW(5, 20, a0, a1, a2, a3);
            if (nw0 > 6) GATHERW(6, 24, a0, a1, a2, a3);
            if (nw0 > 7) GATHERW(7, 28, a0, a1, a2, a3);
            if (nw1 > 0) GATHERW(8, 32, c0, c1, c2, c3);
            if (nw1 > 1) GATHERW(9, 36, c0, c1, c2, c3);
            if (nw1 > 2) GATHERW(10, 40, c0, c1, c2, c3);
            if (nw1 > 3) GATHERW(11, 44, c0, c1, c2, c3);
            if (nw1 > 4) GATHERW(12, 48, c0, c1, c2, c3);
            if (nw1 > 5) GATHERW(13, 52, c0, c1, c2, c3);
            if (nw1 > 6) GATHERW(14, 56, c0, c1, c2, c3);
            if (nw1 > 7) GATHERW(15, 60, c0, c1, c2, c3);
            #undef GATHERW
        }
        float wk = s * (((a0 + a1) + (a2 + a3)) + ((c0 + c1) + (c2 + c3)));
        if ((it & 3) == 3) {
            // full normalization (exact reference formula)
            float t2 = wk * wk;
            for (int off = 32; off; off >>= 1) t2 += __shfl_down(t2, off);
            if ((tid & 63) == 0) red[tid >> 6] = t2;
            if (tid == 0) convflag = 1;
            __syncthreads();
            float tot = 0.f;
            #pragma unroll
            for (int x = 0; x < 8; x++) tot += red[x];
            v = wk / (sqrtf(tot) + 1e-8f);
            bool eq = (__float_as_uint(v) == __float_as_uint(vnprev));
            vnprev = v;
            uu[UADDR(row)] = s * v;
            if (!eq) convflag = 0;
            __syncthreads();
            if (convflag) break;   // bitwise fixed point: remaining iters identity
        } else {
            // deferred: direction-only update (linear iteration)
            uu[UADDR(row)] = s * wk;
            __syncthreads();       // also WAR-protects T for next iter's build
        }
    }
    ev[row] = v;
    __syncthreads();
    for (int kk = 2; kk <= 512; kk <<= 1) {
        for (int j = kk >> 1; j; j >>= 1) {
            if (tid < 256) {
                int i = ((tid & ~(j - 1)) << 1) | (tid & (j - 1));
                int p = i | j;
                float x = ev[i], y = ev[p];
                bool up = (i & kk) == 0;
                if (up ? (x < y) : (x > y)) { ev[i] = y; ev[p] = x; }
            }
            __syncthreads();
        }
    }
    float h0 = b1[row];
    #pragma unroll 8
    for (int l = 0; l < 256; l++)
        h0 += ev[l] * W1[(size_t)l * KK + row];
    float h1 = 0.f;
    #pragma unroll 8
    for (int l = 256; l < 512; l++)
        h1 += ev[l] * W1[(size_t)l * KK + row];
    float hv = fmaxf(h0 + h1, 0.f);
    float term = hv * W2[row];
    for (int off = 32; off; off >>= 1) term += __shfl_down(term, off);
    if ((tid & 63) == 0) red[tid >> 6] = term;
    __syncthreads();
    if (tid == 0) {
        float sc = 0.f;
        #pragma unroll
        for (int x = 0; x < 8; x++) sc += red[x];
        sc += b2[0];
        out[pair] = 1.f / (1.f + expf(-sc));
        out[NPAIR + pair] = (pair & 1) ? 0.f : 1.f;
    }
}

extern "C" void kernel_launch(void* const* d_in, const int* in_sizes, int n_in,
                              void* d_out, int out_size, void* d_ws, size_t ws_size,
                              hipStream_t stream) {
    (void)in_sizes; (void)n_in; (void)out_size; (void)ws_size;
    const float* rt    = (const float*)d_in[0];
    const float* cents = (const float*)d_in[1];
    const float* attn  = (const float*)d_in[2];
    const float* sas   = (const float*)d_in[3];
    const int* num_rt  = (const int*)d_in[4];
    const int* anc     = (const int*)d_in[5];
    const int* pos     = (const int*)d_in[6];
    const int* neg     = (const int*)d_in[7];
    const float* Win   = (const float*)d_in[8];
    const float* bin   = (const float*)d_in[9];
    const float* W1    = (const float*)d_in[10];
    const float* b1    = (const float*)d_in[11];
    const float* W2    = (const float*)d_in[12];
    const float* b2    = (const float*)d_in[13];

    float* ws = (float*)d_ws;
    _Float16* feath = (_Float16*)ws;
    _Float16* featl = (_Float16*)(ws + 4194304);
    float* normF = ws + 8388608;
    float* centk = ws + 8421376;
    float* sbuf  = ws + 8552448;
    int* topidx  = (int*)(ws + 8617984);
    int* neffp   = (int*)(ws + 8650752);
    unsigned* gmask = (unsigned*)(ws + 8716352);
    _Float16* wth = (_Float16*)(ws + 8716352 + 786432);
    _Float16* wtl = (_Float16*)(ws + 8716352 + 819200);
    float* partv = (float*)(ws + 9764928);
    int*   partl = (int*)(ws + 10027072);
    float* partd = (float*)(ws + 10289216);
    float* out = (float*)d_out;

    prep_kernel<<<80, 512, 0, stream>>>(Win, wth, wtl, attn, cents, sas, num_rt, topidx, neffp, centk);
    feat_mfma<<<dim3(256, 2), 256, 0, stream>>>(rt, topidx, wth, wtl, bin, feath, featl);
    norm_kernel<<<2048, 256, 0, stream>>>(feath, featl, normF);
    argmin_mfma<<<512, 512, 0, stream>>>(feath, featl, normF, anc, pos, neg, partv, partl, partd);
    geo_kernel<<<dim3(2, 4, 128), 256, 0, stream>>>(centk, partv, partl, partd, normF, neffp, anc, pos, neg, sbuf, gmask);
    power_kernel<<<128, 512, 0, stream>>>(gmask, sbuf, neffp, anc, pos, neg, W1, b1, W2, b2, out);
}